// Round 1
// baseline (2299.231 us; speedup 1.0000x reference)
//
#include <hip/hip_runtime.h>
#include <hip/hip_bf16.h>
#include <math.h>

#define B_    2
#define S_    2048
#define DIN   2048
#define DOUT  2048
#define H_    16
#define RD_   64
#define L_    512
#define HD_   128
#define BS_   (B_*S_)   // 4096

typedef __attribute__((ext_vector_type(8))) short bf16x8;
typedef __attribute__((ext_vector_type(4))) float f32x4;

__device__ __forceinline__ short f2bs(float f) {
    __hip_bfloat16 h = __float2bfloat16(f);
    return *reinterpret_cast<short*>(&h);
}
__device__ __forceinline__ float bs2f(short s) {
    unsigned u = ((unsigned)(unsigned short)s) << 16;
    return __uint_as_float(u);
}

// global -> LDS direct DMA, 16 B per lane. LDS dest must be wave-uniform base
// (HW adds lane*16); global src is per-lane.
__device__ __forceinline__ void gld16(const void* g, void* l) {
    __builtin_amdgcn_global_load_lds(
        (const __attribute__((address_space(1))) unsigned int*)g,
        (__attribute__((address_space(3))) unsigned int*)l, 16, 0, 0);
}

// ---------------------------------------------------------------------------
// fp32 -> bf16 cast, 8 elems/thread. n8 = n/8.
// ---------------------------------------------------------------------------
__global__ __launch_bounds__(256) void cast_bf(const float* __restrict__ in,
                                               short* __restrict__ out, int n8)
{
    int i = blockIdx.x * 256 + threadIdx.x;
    if (i >= n8) return;
    float4 a = ((const float4*)in)[i*2], b = ((const float4*)in)[i*2+1];
    bf16x8 t;
    t[0]=f2bs(a.x); t[1]=f2bs(a.y); t[2]=f2bs(a.z); t[3]=f2bs(a.w);
    t[4]=f2bs(b.x); t[5]=f2bs(b.y); t[6]=f2bs(b.z); t[7]=f2bs(b.w);
    ((bf16x8*)out)[i] = t;
}

// ---------------------------------------------------------------------------
// bf16 MFMA NT GEMM: C[m][n] = sum_k A[m][k]*B[n][k].  M=grid.y*128, K%32==0.
// ---------------------------------------------------------------------------
__global__ __launch_bounds__(256, 4) void gemm_bf(
    const short* __restrict__ A, const short* __restrict__ Bw,
    float* __restrict__ Cf, short* __restrict__ Cb, int N, int K)
{
    __shared__ short As[128*40];
    __shared__ short Bs[128*40];
    const int tid = threadIdx.x;
    const int m0 = blockIdx.y << 7, n0 = blockIdx.x << 7;
    const int w = tid >> 6, lane = tid & 63;
    const int quad = lane >> 4, n16 = lane & 15;
    const int mw = (w & 1) << 6, nw = (w >> 1) << 6;

    f32x4 acc[4][4];
    #pragma unroll
    for (int mt = 0; mt < 4; mt++)
        #pragma unroll
        for (int nt = 0; nt < 4; nt++) acc[mt][nt] = (f32x4){0.f,0.f,0.f,0.f};

    for (int k0 = 0; k0 < K; k0 += 32) {
        #pragma unroll
        for (int i = 0; i < 2; i++) {
            int c = i*256 + tid;
            int m = c >> 2, kc = c & 3;
            *(bf16x8*)(As + m*40 + kc*8) =
                *(const bf16x8*)(A + (long long)(m0 + m)*K + k0 + kc*8);
            *(bf16x8*)(Bs + m*40 + kc*8) =
                *(const bf16x8*)(Bw + (long long)(n0 + m)*K + k0 + kc*8);
        }
        __syncthreads();
        bf16x8 af[4], bfr[4];
        #pragma unroll
        for (int t = 0; t < 4; t++) {
            af[t]  = *(const bf16x8*)(As + (mw + t*16 + n16)*40 + quad*8);
            bfr[t] = *(const bf16x8*)(Bs + (nw + t*16 + n16)*40 + quad*8);
        }
        #pragma unroll
        for (int mt = 0; mt < 4; mt++)
            #pragma unroll
            for (int nt = 0; nt < 4; nt++)
                acc[mt][nt] = __builtin_amdgcn_mfma_f32_16x16x32_bf16(
                                  af[mt], bfr[nt], acc[mt][nt], 0, 0, 0);
        __syncthreads();
    }

    #pragma unroll
    for (int mt = 0; mt < 4; mt++)
        #pragma unroll
        for (int nt = 0; nt < 4; nt++)
            #pragma unroll
            for (int r = 0; r < 4; r++) {
                long long row = m0 + mw + mt*16 + quad*4 + r;
                int col = n0 + nw + nt*16 + n16;
                if (Cf) Cf[row*(long long)N + col] = acc[mt][nt][r];
                else    Cb[row*(long long)N + col] = f2bs(acc[mt][nt][r]);
            }
}

// ---------------------------------------------------------------------------
// RMSNorm rows of 512 (fp32 in) -> bf16 out
// ---------------------------------------------------------------------------
__global__ __launch_bounds__(256) void rmsnorm_bf(const float* __restrict__ ckv,
                                                  const float* __restrict__ w,
                                                  short* __restrict__ out)
{
    const int row = blockIdx.x;
    const int tid = threadIdx.x;
    const float* p = ckv + (long long)row * L_;
    float v0 = p[tid], v1 = p[tid + 256];
    float ss = v0 * v0 + v1 * v1;
    #pragma unroll
    for (int o = 32; o >= 1; o >>= 1) ss += __shfl_xor(ss, o);
    __shared__ float wsum[4];
    if ((tid & 63) == 0) wsum[tid >> 6] = ss;
    __syncthreads();
    float tot = wsum[0] + wsum[1] + wsum[2] + wsum[3];
    float scale = rsqrtf(tot * (1.0f / (float)L_) + 1e-6f);
    out[(long long)row * L_ + tid]       = f2bs(v0 * scale * w[tid]);
    out[(long long)row * L_ + tid + 256] = f2bs(v1 * scale * w[tid + 256]);
}

// ---------------------------------------------------------------------------
// c_kv_T[b][n][t] = c_kv_bf[b][t][n]   grid (S/64, 512/64, B)
// ---------------------------------------------------------------------------
__global__ __launch_bounds__(256) void ckv_transpose(const short* __restrict__ in,
                                                     short* __restrict__ out)
{
    __shared__ short tile[64][72];
    const int b = blockIdx.z, t0 = blockIdx.x * 64, n0 = blockIdx.y * 64;
    const int tid = threadIdx.x;
    #pragma unroll
    for (int i = 0; i < 16; i++) {
        int idx = i*256 + tid, r = idx >> 6, c = idx & 63;
        tile[r][c] = in[((long long)b*S_ + t0 + r)*512 + n0 + c];
    }
    __syncthreads();
    #pragma unroll
    for (int i = 0; i < 16; i++) {
        int idx = i*256 + tid, r = idx >> 6, c = idx & 63;
        out[((long long)b*512 + n0 + r)*2048 + t0 + c] = tile[c][r];
    }
}

// ---------------------------------------------------------------------------
// w_uk_bf[h][l][d] = bf16(W_UK[h*HD + d][l])
// ---------------------------------------------------------------------------
__global__ __launch_bounds__(256) void transpose_wuk_bf(const float* __restrict__ W_UK,
                                                        short* __restrict__ w_uk_bf)
{
    long long idx = (long long)blockIdx.x * 256 + threadIdx.x;  // H*L*HD
    int d = (int)(idx % HD_);
    long long t = idx / HD_;
    int l = (int)(t % L_);
    int h = (int)(t / L_);
    w_uk_bf[idx] = f2bs(W_UK[(long long)(h * HD_ + d) * L_ + l]);
}

__global__ __launch_bounds__(256) void cast_wuv(const float* __restrict__ in,
                                                short* __restrict__ out)
{
    long long idx = (long long)blockIdx.x * 256 + threadIdx.x;  // 2048*512
    out[idx] = f2bs(in[idx]);
}

// ---------------------------------------------------------------------------
// RoPE in place on bf16 q (cols 2048+h*64..) and bf16 kr (head-major cols)
// ---------------------------------------------------------------------------
__global__ __launch_bounds__(256) void rope_kernel(short* __restrict__ q_bf,
                                                   short* __restrict__ kr_bf,
                                                   const int* __restrict__ offp)
{
    const int offset = offp[0];
    long long idx = (long long)blockIdx.x * 256 + threadIdx.x;  // (B*S)*H*32
    int r = (int)(idx & 31);
    long long t = idx >> 5;
    int h = (int)(t % H_);
    long long m = t / H_;
    int s = (int)(m % S_);

    float inv = (float)exp(-9.210340371976184 * ((double)r / 32.0));
    float ang = (float)(offset + s) * inv;
    float sn, cs;
    sincosf(ang, &sn, &cs);

    short* q = q_bf + m * 3072 + DOUT + h * RD_;
    float x1 = bs2f(q[r]), x2 = bs2f(q[r + 32]);
    q[r]      = f2bs(x1 * cs - x2 * sn);
    q[r + 32] = f2bs(x2 * cs + x1 * sn);

    short* kk = kr_bf + m * (H_ * RD_) + h * RD_;
    x1 = bs2f(kk[r]); x2 = bs2f(kk[r + 32]);
    kk[r]      = f2bs(x1 * cs - x2 * sn);
    kk[r + 32] = f2bs(x2 * cs + x1 * sn);
}

// ---------------------------------------------------------------------------
// MFMA flash latent attention v3 (R6).
// Grid (S/128, B*H), 512 thr = 8 waves; wave w owns q-rows w*16..w*16+15.
// R6 changes vs v2.1 (evidence: VGPR_Count=128 + WRITE_SIZE=531MB ~= 515MB
// spill + 16MB ctx -> the R5 scratch spill was NEVER fixed; scratch working
// set ~31MB > L2 -> HBM-latency spill reloads inside the K/V loop = the
// 40K-cycle tiles behind MfmaUtil 5.8%):
//  1. global_load_lds DMA staging for K/V/rope (frees ~32 arch VGPRs of
//     reg-staging buffers, the spill margin). Linear LDS tiles (DMA needs
//     uniform-base + lane*16); bank conflicts fixed by XOR-swizzling the
//     *source* lane address (granule l^(row&7)) and the read offsets.
//  2. P gets a dedicated LDS region (no K overlay); exp() stored to LDS as
//     bf16 immediately (kills the p[4][4] = 16 arch regs).
//  3. Counted-vmcnt pipeline: K(t+1) DMA issued under PV(t), V(t) DMA issued
//     under scores(t); raw s_barrier + asm waitcnt (syncthreads would drain
//     vmcnt(0) and kill the overlap).
//  4. Defer-max (THR=8): skip the 128-reg Oacc rescale when no row max grew.
// LDS map (shorts): Kc[64][512]@0  Krope[64][64]@32768  Vt[512][64]@36864
//                   P[8][16][72]@69632  -> 157,696 B (1 block/CU).
// ---------------------------------------------------------------------------
#define KC0 0
#define KR0 32768
#define VT0 36864
#define PP0 69632

__global__ __launch_bounds__(512)
__attribute__((amdgpu_waves_per_eu(2, 2)))
void flash_mfma(
    const short* __restrict__ q_bf,     // [BS][3072] bf16, rope cols rotated
    const short* __restrict__ c_kv_bf,  // [BS][512]  bf16
    const short* __restrict__ c_kv_T,   // [B][512][2048] bf16
    const short* __restrict__ kr_bf,    // [BS][1024] bf16, rotated
    const short* __restrict__ w_uk_bf,  // [H][512][128] bf16
    const short* __restrict__ w_uv_bf,  // [2048][512] bf16
    const int* __restrict__ offp,
    short* __restrict__ ctx_bf)         // [BS][2048] bf16
{
    __shared__ short lds[78848];
    const int offset = offp[0];
    const int bh = blockIdx.y;
    const int b = bh >> 4, h = bh & 15;
    const int r0 = (int)(gridDim.x - 1 - blockIdx.x) * 128;  // longest first
    const int tid = threadIdx.x;
    const int w = tid >> 6, lane = tid & 63;
    const int quad = lane >> 4, n16 = lane & 15;
    const int rx = n16 & 7;              // read-side XOR swizzle key
    const float scale = rsqrtf((float)(HD_ + RD_));

    // ---- prologue: q_abs = q_content @ w_uk^T (MFMA) -> Q tile [128][584] ----
    {
        const long long qrow = (long long)b*S_ + r0 + w*16 + n16;
        const short* qp = q_bf + qrow*3072 + h*HD_ + quad*8;
        bf16x8 qc[4];
        #pragma unroll
        for (int ks = 0; ks < 4; ks++) qc[ks] = *(const bf16x8*)(qp + ks*32);
        #pragma unroll 4
        for (int v = 0; v < 32; v++) {
            f32x4 a = {0.f,0.f,0.f,0.f};
            const short* wp = w_uk_bf + ((long long)(h*512 + v*16 + n16) << 7) + quad*8;
            #pragma unroll
            for (int ks = 0; ks < 4; ks++)
                a = __builtin_amdgcn_mfma_f32_16x16x32_bf16(
                        qc[ks], *(const bf16x8*)(wp + ks*32), a, 0, 0, 0);
            #pragma unroll
            for (int r = 0; r < 4; r++)
                lds[(w*16 + quad*4 + r)*584 + v*16 + n16] = f2bs(a[r]);
        }
        // rope cols 512..575, vectorized copy
        #pragma unroll
        for (int i = 0; i < 2; i++) {
            int idx = i*512 + tid, rr = idx >> 3, g = idx & 7;
            *(bf16x8*)(lds + rr*584 + 512 + g*8) =
                *(const bf16x8*)(q_bf + ((long long)b*S_ + r0 + rr)*3072
                                 + DOUT + h*RD_ + g*8);
        }
    }
    __syncthreads();
    bf16x8 qf[18];
    {
        const int qb = (w*16 + n16)*584 + quad*8;
        #pragma unroll
        for (int ks = 0; ks < 18; ks++)
            qf[ks] = *(const bf16x8*)(lds + qb + ks*32);
    }
    // qf reads retired everywhere before K(0) DMA overwrites the region
    asm volatile("s_waitcnt lgkmcnt(0)" ::: "memory");
    __builtin_amdgcn_s_barrier();
    __builtin_amdgcn_sched_barrier(0);

    // swizzled-source lane constants (shorts)
    const int gK  = ((lane ^ w) << 3);                   // Kc rows: row&7 == w
    const int gRV = (((lane & 7) ^ (lane >> 3)) << 3);   // rope/V: row&7 == lane>>3

    const short* kc_src = c_kv_bf + (((long long)b*S_) << 9);
    const short* kr_src = kr_bf  + (((long long)b*S_) << 10) + h*RD_;
    const short* v_src  = c_kv_T + (((long long)b*512) << 11);

    int tmax = r0 + 128 + offset;
    if (tmax > S_) tmax = S_;

    // 9 DMA calls: K content (8 rows/wave) + K rope (8 rows/wave)
    auto stageK = [&](int tk) {
        #pragma unroll
        for (int i = 0; i < 8; i++) {
            int row = i*8 + w;
            gld16(kc_src + (((long long)(tk + row)) << 9) + gK,
                  (void*)(lds + KC0 + row*512));
        }
        gld16(kr_src + (((long long)(tk + w*8 + (lane >> 3))) << 10) + gRV,
              (void*)(lds + KR0 + w*512));
    };
    // 8 DMA calls: V (64 latent rows/wave)
    auto stageV = [&](int tk) {
        #pragma unroll
        for (int j = 0; j < 8; j++) {
            int n = j*64 + w*8 + (lane >> 3);
            gld16(v_src + (((long long)n) << 11) + tk + gRV,
                  (void*)(lds + VT0 + (j*64 + w*8)*64));
        }
    };

    stageK(0);   // in flight through iter-0 top; drained at (b1)

    f32x4 Oacc[32];
    #pragma unroll
    for (int v = 0; v < 32; v++) Oacc[v] = (f32x4){0.f,0.f,0.f,0.f};
    float mrun[4] = {-INFINITY,-INFINITY,-INFINITY,-INFINITY};
    float lrun[4] = {0.f,0.f,0.f,0.f};

    for (int t0 = 0; t0 < tmax; t0 += 64) {
        // (a): all waves done reading V/P of prev iter (K DMA stays in flight)
        asm volatile("s_waitcnt lgkmcnt(0)" ::: "memory");
        __builtin_amdgcn_s_barrier();
        __builtin_amdgcn_sched_barrier(0);

        stageV(t0);                                  // hides under scores

        // (b1): own K loads done (9 oldest of 17); barrier -> K visible to all
        asm volatile("s_waitcnt vmcnt(8)" ::: "memory");
        __builtin_amdgcn_s_barrier();
        __builtin_amdgcn_sched_barrier(0);

        // ---- scores ----
        f32x4 Sf[4];
        #pragma unroll
        for (int nt = 0; nt < 4; nt++) {
            f32x4 a = {0.f,0.f,0.f,0.f};
            const short* kc = lds + KC0 + (nt*16 + n16)*512;
            #pragma unroll
            for (int ks = 0; ks < 16; ks++)
                a = __builtin_amdgcn_mfma_f32_16x16x32_bf16(
                        qf[ks],
                        *(const bf16x8*)(kc + (((ks*4 + quad) ^ rx) << 3)),
                        a, 0, 0, 0);
            const short* kr = lds + KR0 + (nt*16 + n16)*64;
            a = __builtin_amdgcn_mfma_f32_16x16x32_bf16(
                    qf[16], *(const bf16x8*)(kr + ((quad ^ rx) << 3)), a, 0, 0, 0);
            a = __builtin_amdgcn_mfma_f32_16x16x32_bf16(
                    qf[17], *(const bf16x8*)(kr + (((quad + 4) ^ rx) << 3)), a, 0, 0, 0);
            Sf[nt] = a;
        }

        // ---- softmax (defer-max), P -> LDS as bf16 immediately ----
        float al[4];
        bool need = false;
        #pragma unroll
        for (int r = 0; r < 4; r++) {
            const int srow = r0 + w*16 + quad*4 + r;
            float e0[4]; float tm = -INFINITY;
            #pragma unroll
            for (int nt = 0; nt < 4; nt++) {
                int t = t0 + nt*16 + n16;
                float s = (t <= srow + offset) ? Sf[nt][r]*scale : -INFINITY;
                e0[nt] = s; tm = fmaxf(tm, s);
            }
            tm = fmaxf(tm, __shfl_xor(tm, 1));
            tm = fmaxf(tm, __shfl_xor(tm, 2));
            tm = fmaxf(tm, __shfl_xor(tm, 4));
            tm = fmaxf(tm, __shfl_xor(tm, 8));
            if (tm > mrun[r] + 8.f) {
                al[r] = __expf(mrun[r] - tm);
                mrun[r] = tm;
                need = true;
            } else al[r] = 1.f;
            float ps = 0.f;
            #pragma unroll
            for (int nt = 0; nt < 4; nt++) {
                float ex = __expf(e0[nt] - mrun[r]);
                ps += ex;
                lds[PP0 + w*1152 + (quad*4 + r)*72 + nt*16 + n16] = f2bs(ex);
            }
            ps += __shfl_xor(ps, 1);
            ps += __shfl_xor(ps, 2);
            ps += __shfl_xor(ps, 4);
            ps += __shfl_xor(ps, 8);
            lrun[r] = lrun[r]*al[r] + ps;
        }
        if (__any((int)need)) {
            #pragma unroll
            for (int v = 0; v < 32; v++) {
                Oacc[v][0] *= al[0]; Oacc[v][1] *= al[1];
                Oacc[v][2] *= al[2]; Oacc[v][3] *= al[3];
            }
        }

        // (b2): V ready everywhere; K region free (scores done by all)
        asm volatile("s_waitcnt vmcnt(0)" ::: "memory");
        __builtin_amdgcn_s_barrier();
        __builtin_amdgcn_sched_barrier(0);

        if (t0 + 64 < tmax) stageK(t0 + 64);         // hides under PV

        // ---- PV ----
        bf16x8 pf0 = *(const bf16x8*)(lds + PP0 + w*1152 + n16*72 + quad*8);
        bf16x8 pf1 = *(const bf16x8*)(lds + PP0 + w*1152 + n16*72 + 32 + quad*8);
        const int vo0 = ((quad    ) ^ rx) << 3;
        const int vo1 = ((quad + 4) ^ rx) << 3;
        #pragma unroll
        for (int v = 0; v < 32; v++) {
            const short* vb = lds + VT0 + (v*16 + n16)*64;
            Oacc[v] = __builtin_amdgcn_mfma_f32_16x16x32_bf16(
                          pf0, *(const bf16x8*)(vb + vo0), Oacc[v], 0, 0, 0);
            Oacc[v] = __builtin_amdgcn_mfma_f32_16x16x32_bf16(
                          pf1, *(const bf16x8*)(vb + vo1), Oacc[v], 0, 0, 0);
        }
    }

    // ---- epilogue: ctx = (O/l) @ W_UV^T via MFMA ----
    asm volatile("s_waitcnt lgkmcnt(0)" ::: "memory");
    __builtin_amdgcn_s_barrier();
    __builtin_amdgcn_sched_barrier(0);
    float inv[4];
    #pragma unroll
    for (int r = 0; r < 4; r++) inv[r] = 1.0f / lrun[r];
    #pragma unroll
    for (int v = 0; v < 32; v++)
        #pragma unroll
        for (int r = 0; r < 4; r++)
            lds[(w*16 + quad*4 + r)*520 + v*16 + n16] = f2bs(Oacc[v][r]*inv[r]);
    __syncthreads();
    f32x4 cacc[8];
    #pragma unroll
    for (int d = 0; d < 8; d++) cacc[d] = (f32x4){0.f,0.f,0.f,0.f};
    const int ob = (w*16 + n16)*520 + quad*8;
    for (int ks = 0; ks < 16; ks++) {
        bf16x8 of = *(const bf16x8*)(lds + ob + ks*32);
        #pragma unroll
        for (int d = 0; d < 8; d++) {
            const short* wp = w_uv_bf + (((long long)(h*HD_ + d*16 + n16)) << 9)
                            + ks*32 + quad*8;
            cacc[d] = __builtin_amdgcn_mfma_f32_16x16x32_bf16(
                          of, *(const bf16x8*)wp, cacc[d], 0, 0, 0);
        }
    }
    #pragma unroll
    for (int d = 0; d < 8; d++)
        #pragma unroll
        for (int r = 0; r < 4; r++) {
            long long row = (long long)b*S_ + r0 + w*16 + quad*4 + r;
            ctx_bf[row*2048 + h*HD_ + d*16 + n16] = f2bs(cacc[d][r]);
        }
}

// ---------------------------------------------------------------------------
extern "C" void kernel_launch(void* const* d_in, const int* in_sizes, int n_in,
                              void* d_out, int out_size, void* d_ws, size_t ws_size,
                              hipStream_t stream)
{
    const float* x       = (const float*)d_in[0];
    const float* W_DKV   = (const float*)d_in[1];
    const float* W_KRope = (const float*)d_in[2];
    const float* W_Q     = (const float*)d_in[3];
    const float* W_UK    = (const float*)d_in[4];
    const float* W_UV    = (const float*)d_in[5];
    const float* W_O     = (const float*)d_in[6];
    const float* kvnw    = (const float*)d_in[7];
    const int*   offp    = (const int*)d_in[8];
    float* out = (float*)d_out;

    float* ws = (float*)d_ws;
    float* c_kv    = ws;                        // 2,097,152 f
    short* x_bf    = (short*)(c_kv + 2097152);  // 8,388,608
    short* q_bf    = x_bf    + 8388608;         // 12,582,912
    short* kr_bf   = q_bf    + 12582912;        // 4,194,304
    short* c_kv_bf = kr_bf   + 4194304;         // 2,097,152
    short* c_kv_T  = c_kv_bf + 2097152;         // 2,097,152
    short* w_uk_bf = c_kv_T  + 2097152;         // 1,048,576
    short* w_uv_bf = w_uk_bf + 1048576;         // 1,048,576
    short* wdkv_bf = w_uv_bf + 1048576;         // 1,048,576
    short* wkr_bf  = wdkv_bf + 1048576;         // 2,097,152
    short* wq_bf   = wkr_bf  + 2097152;         // 6,291,456
    short* wo_bf   = wq_bf   + 6291456;         // 4,194,304
    short* ctx_bf  = wo_bf   + 4194304;         // 8,388,608
    // total ~115 MiB

    dim3 blk(256);

    // casts to bf16
    cast_bf<<<4096, blk, 0, stream>>>(x, x_bf, 1048576);
    cast_bf<<<512,  blk, 0, stream>>>(W_DKV, wdkv_bf, 131072);
    cast_bf<<<1024, blk, 0, stream>>>(W_KRope, wkr_bf, 262144);
    cast_bf<<<3072, blk, 0, stream>>>(W_Q, wq_bf, 786432);
    cast_bf<<<2048, blk, 0, stream>>>(W_O, wo_bf, 524288);
    transpose_wuk_bf<<<4096, blk, 0, stream>>>(W_UK, w_uk_bf);
    cast_wuv<<<4096, blk, 0, stream>>>(W_UV, w_uv_bf);

    // projections (bf16 MFMA)
    gemm_bf<<<dim3(512/128, 32), blk, 0, stream>>>(
        x_bf, wdkv_bf, c_kv, nullptr, 512, 2048);
    rmsnorm_bf<<<4096, blk, 0, stream>>>(c_kv, kvnw, c_kv_bf);
    ckv_transpose<<<dim3(32, 8, 2), blk, 0, stream>>>(c_kv_bf, c_kv_T);
    gemm_bf<<<dim3(1024/128, 32), blk, 0, stream>>>(
        x_bf, wkr_bf, nullptr, kr_bf, 1024, 2048);
    gemm_bf<<<dim3(3072/128, 32), blk, 0, stream>>>(
        x_bf, wq_bf, nullptr, q_bf, 3072, 2048);

    // RoPE in place (bf16)
    rope_kernel<<<8192, blk, 0, stream>>>(q_bf, kr_bf, offp);

    // fused flash latent attention -> ctx (bf16)
    flash_mfma<<<dim3(S_/128, B_*H_), dim3(512), 0, stream>>>(
        q_bf, c_kv_bf, c_kv_T, kr_bf, w_uk_bf, w_uv_bf, offp, ctx_bf);

    // out = ctx @ W_O^T (fp32 out)
    gemm_bf<<<dim3(2048/128, 32), blk, 0, stream>>>(
        ctx_bf, wo_bf, out, nullptr, 2048, 2048);
}

// Round 2
// 582.777 us; speedup vs baseline: 3.9453x; 3.9453x over previous
//
#include <hip/hip_runtime.h>
#include <hip/hip_bf16.h>
#include <math.h>

#define B_    2
#define S_    2048
#define DIN   2048
#define DOUT  2048
#define H_    16
#define RD_   64
#define L_    512
#define HD_   128
#define BS_   (B_*S_)   // 4096

typedef __attribute__((ext_vector_type(8))) short bf16x8;
typedef __attribute__((ext_vector_type(4))) float f32x4;

__device__ __forceinline__ short f2bs(float f) {
    __hip_bfloat16 h = __float2bfloat16(f);
    return *reinterpret_cast<short*>(&h);
}
__device__ __forceinline__ float bs2f(short s) {
    unsigned u = ((unsigned)(unsigned short)s) << 16;
    return __uint_as_float(u);
}

// global -> LDS direct DMA, 16 B per lane. LDS dest is wave-uniform base
// (HW adds lane*16); global src is per-lane (enables source-side swizzle).
__device__ __forceinline__ void gld16(const void* g, void* l) {
    __builtin_amdgcn_global_load_lds(
        (const __attribute__((address_space(1))) unsigned int*)g,
        (__attribute__((address_space(3))) unsigned int*)l, 16, 0, 0);
}

// ---------------------------------------------------------------------------
// fp32 -> bf16 cast, 8 elems/thread. n8 = n/8.
// ---------------------------------------------------------------------------
__global__ __launch_bounds__(256) void cast_bf(const float* __restrict__ in,
                                               short* __restrict__ out, int n8)
{
    int i = blockIdx.x * 256 + threadIdx.x;
    if (i >= n8) return;
    float4 a = ((const float4*)in)[i*2], b = ((const float4*)in)[i*2+1];
    bf16x8 t;
    t[0]=f2bs(a.x); t[1]=f2bs(a.y); t[2]=f2bs(a.z); t[3]=f2bs(a.w);
    t[4]=f2bs(b.x); t[5]=f2bs(b.y); t[6]=f2bs(b.z); t[7]=f2bs(b.w);
    ((bf16x8*)out)[i] = t;
}

// ---------------------------------------------------------------------------
// bf16 MFMA NT GEMM: C[m][n] = sum_k A[m][k]*B[n][k].  M=grid.y*128, K%32==0.
// ---------------------------------------------------------------------------
__global__ __launch_bounds__(256, 4) void gemm_bf(
    const short* __restrict__ A, const short* __restrict__ Bw,
    float* __restrict__ Cf, short* __restrict__ Cb, int N, int K)
{
    __shared__ short As[128*40];
    __shared__ short Bs[128*40];
    const int tid = threadIdx.x;
    const int m0 = blockIdx.y << 7, n0 = blockIdx.x << 7;
    const int w = tid >> 6, lane = tid & 63;
    const int quad = lane >> 4, n16 = lane & 15;
    const int mw = (w & 1) << 6, nw = (w >> 1) << 6;

    f32x4 acc[4][4];
    #pragma unroll
    for (int mt = 0; mt < 4; mt++)
        #pragma unroll
        for (int nt = 0; nt < 4; nt++) acc[mt][nt] = (f32x4){0.f,0.f,0.f,0.f};

    for (int k0 = 0; k0 < K; k0 += 32) {
        #pragma unroll
        for (int i = 0; i < 2; i++) {
            int c = i*256 + tid;
            int m = c >> 2, kc = c & 3;
            *(bf16x8*)(As + m*40 + kc*8) =
                *(const bf16x8*)(A + (long long)(m0 + m)*K + k0 + kc*8);
            *(bf16x8*)(Bs + m*40 + kc*8) =
                *(const bf16x8*)(Bw + (long long)(n0 + m)*K + k0 + kc*8);
        }
        __syncthreads();
        bf16x8 af[4], bfr[4];
        #pragma unroll
        for (int t = 0; t < 4; t++) {
            af[t]  = *(const bf16x8*)(As + (mw + t*16 + n16)*40 + quad*8);
            bfr[t] = *(const bf16x8*)(Bs + (nw + t*16 + n16)*40 + quad*8);
        }
        #pragma unroll
        for (int mt = 0; mt < 4; mt++)
            #pragma unroll
            for (int nt = 0; nt < 4; nt++)
                acc[mt][nt] = __builtin_amdgcn_mfma_f32_16x16x32_bf16(
                                  af[mt], bfr[nt], acc[mt][nt], 0, 0, 0);
        __syncthreads();
    }

    #pragma unroll
    for (int mt = 0; mt < 4; mt++)
        #pragma unroll
        for (int nt = 0; nt < 4; nt++)
            #pragma unroll
            for (int r = 0; r < 4; r++) {
                long long row = m0 + mw + mt*16 + quad*4 + r;
                int col = n0 + nw + nt*16 + n16;
                if (Cf) Cf[row*(long long)N + col] = acc[mt][nt][r];
                else    Cb[row*(long long)N + col] = f2bs(acc[mt][nt][r]);
            }
}

// ---------------------------------------------------------------------------
// RMSNorm rows of 512 (fp32 in) -> bf16 out
// ---------------------------------------------------------------------------
__global__ __launch_bounds__(256) void rmsnorm_bf(const float* __restrict__ ckv,
                                                  const float* __restrict__ w,
                                                  short* __restrict__ out)
{
    const int row = blockIdx.x;
    const int tid = threadIdx.x;
    const float* p = ckv + (long long)row * L_;
    float v0 = p[tid], v1 = p[tid + 256];
    float ss = v0 * v0 + v1 * v1;
    #pragma unroll
    for (int o = 32; o >= 1; o >>= 1) ss += __shfl_xor(ss, o);
    __shared__ float wsum[4];
    if ((tid & 63) == 0) wsum[tid >> 6] = ss;
    __syncthreads();
    float tot = wsum[0] + wsum[1] + wsum[2] + wsum[3];
    float scale = rsqrtf(tot * (1.0f / (float)L_) + 1e-6f);
    out[(long long)row * L_ + tid]       = f2bs(v0 * scale * w[tid]);
    out[(long long)row * L_ + tid + 256] = f2bs(v1 * scale * w[tid + 256]);
}

// ---------------------------------------------------------------------------
// V_upT[b*2048 + c][t] = V_up[b*2048 + t][c]    (c = h*128+d)
// grid (S/64, 2048/64, B)
// ---------------------------------------------------------------------------
__global__ __launch_bounds__(256) void vup_transpose(const short* __restrict__ in,
                                                     short* __restrict__ out)
{
    __shared__ short tile[64][72];
    const int b = blockIdx.z, t0 = blockIdx.x * 64, c0 = blockIdx.y * 64;
    const int tid = threadIdx.x;
    #pragma unroll
    for (int i = 0; i < 16; i++) {
        int idx = i*256 + tid, r = idx >> 6, c = idx & 63;
        tile[r][c] = in[((long long)(b*S_ + t0 + r))*2048 + c0 + c];
    }
    __syncthreads();
    #pragma unroll
    for (int i = 0; i < 16; i++) {
        int idx = i*256 + tid, r = idx >> 6, c = idx & 63;
        out[((long long)(b*S_ + c0 + r))*2048 + t0 + c] = tile[c][r];
    }
}

// ---------------------------------------------------------------------------
// RoPE in place on bf16 q (cols 2048+h*64..) and bf16 kr (head-major cols)
// ---------------------------------------------------------------------------
__global__ __launch_bounds__(256) void rope_kernel(short* __restrict__ q_bf,
                                                   short* __restrict__ kr_bf,
                                                   const int* __restrict__ offp)
{
    const int offset = offp[0];
    long long idx = (long long)blockIdx.x * 256 + threadIdx.x;  // (B*S)*H*32
    int r = (int)(idx & 31);
    long long t = idx >> 5;
    int h = (int)(t % H_);
    long long m = t / H_;
    int s = (int)(m % S_);

    float inv = (float)exp(-9.210340371976184 * ((double)r / 32.0));
    float ang = (float)(offset + s) * inv;
    float sn, cs;
    sincosf(ang, &sn, &cs);

    short* q = q_bf + m * 3072 + DOUT + h * RD_;
    float x1 = bs2f(q[r]), x2 = bs2f(q[r + 32]);
    q[r]      = f2bs(x1 * cs - x2 * sn);
    q[r + 32] = f2bs(x2 * cs + x1 * sn);

    short* kk = kr_bf + m * (H_ * RD_) + h * RD_;
    x1 = bs2f(kk[r]); x2 = bs2f(kk[r + 32]);
    kk[r]      = f2bs(x1 * cs - x2 * sn);
    kk[r + 32] = f2bs(x2 * cs + x1 * sn);
}

// ---------------------------------------------------------------------------
// flash_mha v1 (R7): standard per-head flash attention after absorbing
// W_UK/W_UV into K_up = c_kv@W_UK^T, V_up = c_kv@W_UV^T (prep GEMMs).
// K-dim 192 (128 content + 64 rope), V-dim 128.
// Grid (S/128, B*H), 512 thr = 8 waves; wave w owns q-rows w*16..w*16+15.
// Per-wave state: qf 24 + Oacc 32 + softmax ~110 VGPR total -> NO spill
// (R5/R6 evidence: the absorbed formulation's 230-reg state spilled at the
// 256 budget and scratch vmcnt waits poisoned every pipeline attempt).
// 64-token K/V tiles, double-buffered; 5 gld16/wave/tile; one
// vmcnt(0)+s_barrier per tile; prefetch issued right after the barrier.
// LDS (shorts): KC[2][64][128]@0  KR[2][64][64]@16384  VT[2][128][64]@24576
//               P[8][1152]@40960  -> 100,352 B.
// Bank behavior: row pitches are bank-aligned, so reads XOR-swizzle byte
// offsets with (row&7)<<4 (source-swizzled at staging, m173/T2 pattern) ->
// accesses spread evenly over all 32 banks (8/bank = b128 minimum).
// ---------------------------------------------------------------------------
#define TKC0 0
#define TKR0 16384
#define TVT0 24576
#define TPP0 40960

__global__ __launch_bounds__(512)
__attribute__((amdgpu_waves_per_eu(2, 2)))
void flash_mha(
    const short* __restrict__ q_bf,     // [BS][3072] bf16, rope cols rotated
    const short* __restrict__ K_up,     // [BS][2048] bf16 (h*128+d cols)
    const short* __restrict__ kr_bf,    // [BS][1024] bf16, rotated
    const short* __restrict__ V_upT,    // [B*2048][2048] bf16 (row=h*128+d, col=t)
    const int* __restrict__ offp,
    short* __restrict__ ctx_bf)         // [BS][2048] bf16
{
    __shared__ short lds[50176];
    const int offset = offp[0];
    const int bh = blockIdx.y;
    const int b = bh >> 4, h = bh & 15;
    const int r0 = (int)(gridDim.x - 1 - blockIdx.x) * 128;  // longest first
    const int tid = threadIdx.x;
    const int w = tid >> 6, lane = tid & 63;
    const int quad = lane >> 4, n16 = lane & 15;
    const int rx3 = (n16 & 7) << 3;          // short-offset XOR key (reads)
    const float scale = rsqrtf((float)(HD_ + RD_));

    const int l4 = lane >> 4, g16 = lane & 15;   // 4-rows-of-256B decomp
    const int l8 = lane >> 3, g8 = lane & 7;     // 8-rows-of-128B decomp

    const short* kc_src = K_up  + ((long long)b*S_)*2048 + h*HD_;
    const short* kr_src = kr_bf + ((long long)b*S_)*1024 + h*RD_;
    const short* vt_src = V_upT + ((long long)(b*S_ + h*HD_))*2048;

    // 5 gld16 calls per wave: KC 2 (4 rows each), KR 1 (8 rows), VT 2 (8 rows)
    auto stage = [&](int tk, int bf) {
        #pragma unroll
        for (int j = 0; j < 2; j++) {
            int r4 = (w*2 + j)*4;
            int row = r4 + l4;
            int gs = g16 ^ (row & 7);            // source-side swizzle
            gld16(kc_src + (long long)(tk + row)*2048 + gs*8,
                  (void*)(lds + TKC0 + bf*8192 + r4*128));
        }
        {
            int row = w*8 + l8;
            int gs = g8 ^ (l8 & 7);              // row&7 == l8
            gld16(kr_src + (long long)(tk + row)*1024 + gs*8,
                  (void*)(lds + TKR0 + bf*4096 + w*512));
        }
        #pragma unroll
        for (int j = 0; j < 2; j++) {
            int d8 = (w*2 + j)*8;
            int d = d8 + l8;
            int gs = g8 ^ (l8 & 7);              // d&7 == l8
            gld16(vt_src + (long long)d*2048 + tk + gs*8,
                  (void*)(lds + TVT0 + bf*8192 + d8*64));
        }
    };

    stage(0, 0);

    // Q fragments straight from global (one-time): content 4 + rope 2
    bf16x8 qf[6];
    {
        const short* qp = q_bf + ((long long)(b*S_ + r0 + w*16 + n16))*3072;
        #pragma unroll
        for (int ks = 0; ks < 4; ks++)
            qf[ks] = *(const bf16x8*)(qp + h*HD_ + ks*32 + quad*8);
        #pragma unroll
        for (int ks = 0; ks < 2; ks++)
            qf[4+ks] = *(const bf16x8*)(qp + DOUT + h*RD_ + ks*32 + quad*8);
    }

    f32x4 Oacc[8];
    #pragma unroll
    for (int v = 0; v < 8; v++) Oacc[v] = (f32x4){0.f,0.f,0.f,0.f};
    float mrun[4] = {-INFINITY,-INFINITY,-INFINITY,-INFINITY};
    float lrun[4] = {0.f,0.f,0.f,0.f};

    int tmax = r0 + 128 + offset;
    if (tmax > S_) tmax = S_;

    for (int t0 = 0, bf = 0; t0 < tmax; t0 += 64, bf ^= 1) {
        // own stage(t0) loads landed; barrier -> everyone's landed, and
        // everyone is done reading buffer bf^1 (so it can be overwritten)
        asm volatile("s_waitcnt vmcnt(0)" ::: "memory");
        __builtin_amdgcn_s_barrier();
        __builtin_amdgcn_sched_barrier(0);

        if (t0 + 64 < tmax) stage(t0 + 64, bf ^ 1);   // hides under this tile

        // ---- scores: S[16 rows][64 tok], K-dim 192 ----
        const short* kcb = lds + TKC0 + bf*8192;
        const short* krb = lds + TKR0 + bf*4096;
        f32x4 Sf[4];
        #pragma unroll
        for (int nt = 0; nt < 4; nt++) {
            f32x4 a = {0.f,0.f,0.f,0.f};
            const short* kc = kcb + (nt*16 + n16)*128;
            #pragma unroll
            for (int ks = 0; ks < 4; ks++)
                a = __builtin_amdgcn_mfma_f32_16x16x32_bf16(
                        qf[ks], *(const bf16x8*)(kc + ((ks*32 + quad*8) ^ rx3)),
                        a, 0, 0, 0);
            const short* kr = krb + (nt*16 + n16)*64;
            a = __builtin_amdgcn_mfma_f32_16x16x32_bf16(
                    qf[4], *(const bf16x8*)(kr + ((quad*8) ^ rx3)), a, 0, 0, 0);
            a = __builtin_amdgcn_mfma_f32_16x16x32_bf16(
                    qf[5], *(const bf16x8*)(kr + ((32 + quad*8) ^ rx3)), a, 0, 0, 0);
            Sf[nt] = a;
        }

        // ---- softmax (defer-max THR=8), P -> LDS bf16 immediately ----
        float al[4];
        bool need = false;
        #pragma unroll
        for (int r = 0; r < 4; r++) {
            const int srow = r0 + w*16 + quad*4 + r;
            float e0[4]; float tm = -INFINITY;
            #pragma unroll
            for (int nt = 0; nt < 4; nt++) {
                int t = t0 + nt*16 + n16;
                float s = (t <= srow + offset) ? Sf[nt][r]*scale : -INFINITY;
                e0[nt] = s; tm = fmaxf(tm, s);
            }
            tm = fmaxf(tm, __shfl_xor(tm, 1));
            tm = fmaxf(tm, __shfl_xor(tm, 2));
            tm = fmaxf(tm, __shfl_xor(tm, 4));
            tm = fmaxf(tm, __shfl_xor(tm, 8));
            if (tm > mrun[r] + 8.f) {
                al[r] = __expf(mrun[r] - tm);
                mrun[r] = tm;
                need = true;
            } else al[r] = 1.f;
            float ps = 0.f;
            #pragma unroll
            for (int nt = 0; nt < 4; nt++) {
                float ex = __expf(e0[nt] - mrun[r]);
                ps += ex;
                lds[TPP0 + w*1152 + (quad*4 + r)*72 + nt*16 + n16] = f2bs(ex);
            }
            ps += __shfl_xor(ps, 1);
            ps += __shfl_xor(ps, 2);
            ps += __shfl_xor(ps, 4);
            ps += __shfl_xor(ps, 8);
            lrun[r] = lrun[r]*al[r] + ps;
        }
        if (__any((int)need)) {
            #pragma unroll
            for (int v = 0; v < 8; v++) {
                Oacc[v][0] *= al[0]; Oacc[v][1] *= al[1];
                Oacc[v][2] *= al[2]; Oacc[v][3] *= al[3];
            }
        }

        // ---- PV: O[16 rows][128 dims] += P @ V ----  (P is wave-private)
        const short* vtb = lds + TVT0 + bf*8192;
        bf16x8 pf0 = *(const bf16x8*)(lds + TPP0 + w*1152 + n16*72 + quad*8);
        bf16x8 pf1 = *(const bf16x8*)(lds + TPP0 + w*1152 + n16*72 + 32 + quad*8);
        const int vo0 = (quad*8) ^ rx3, vo1 = (32 + quad*8) ^ rx3;
        #pragma unroll
        for (int v = 0; v < 8; v++) {
            const short* vb = vtb + (v*16 + n16)*64;
            Oacc[v] = __builtin_amdgcn_mfma_f32_16x16x32_bf16(
                          pf0, *(const bf16x8*)(vb + vo0), Oacc[v], 0, 0, 0);
            Oacc[v] = __builtin_amdgcn_mfma_f32_16x16x32_bf16(
                          pf1, *(const bf16x8*)(vb + vo1), Oacc[v], 0, 0, 0);
        }
    }

    // ---- epilogue: ctx = O/l, direct store (no MFMA epilogue anymore) ----
    float inv[4];
    #pragma unroll
    for (int r = 0; r < 4; r++) inv[r] = 1.0f / lrun[r];
    #pragma unroll
    for (int v = 0; v < 8; v++)
        #pragma unroll
        for (int r = 0; r < 4; r++) {
            long long row = (long long)b*S_ + r0 + w*16 + quad*4 + r;
            ctx_bf[row*2048 + h*HD_ + v*16 + n16] = f2bs(Oacc[v][r]*inv[r]);
        }
}

// ---------------------------------------------------------------------------
extern "C" void kernel_launch(void* const* d_in, const int* in_sizes, int n_in,
                              void* d_out, int out_size, void* d_ws, size_t ws_size,
                              hipStream_t stream)
{
    const float* x       = (const float*)d_in[0];
    const float* W_DKV   = (const float*)d_in[1];
    const float* W_KRope = (const float*)d_in[2];
    const float* W_Q     = (const float*)d_in[3];
    const float* W_UK    = (const float*)d_in[4];
    const float* W_UV    = (const float*)d_in[5];
    const float* W_O     = (const float*)d_in[6];
    const float* kvnw    = (const float*)d_in[7];
    const int*   offp    = (const int*)d_in[8];
    float* out = (float*)d_out;

    float* ws = (float*)d_ws;
    float* c_kv    = ws;                        // 2,097,152 f
    short* x_bf    = (short*)(c_kv + 2097152);  // 8,388,608
    short* q_bf    = x_bf    + 8388608;         // 12,582,912
    short* kr_bf   = q_bf    + 12582912;        // 4,194,304
    short* c_kv_bf = kr_bf   + 4194304;         // 2,097,152
    short* wuk_bf  = c_kv_bf + 2097152;         // 1,048,576
    short* wuv_bf  = wuk_bf  + 1048576;         // 1,048,576
    short* wdkv_bf = wuv_bf  + 1048576;         // 1,048,576
    short* wkr_bf  = wdkv_bf + 1048576;         // 2,097,152
    short* wq_bf   = wkr_bf  + 2097152;         // 6,291,456
    short* wo_bf   = wq_bf   + 6291456;         // 4,194,304
    short* ctx_bf  = wo_bf   + 4194304;         // 8,388,608
    short* V_upT   = ctx_bf  + 8388608;         // 8,388,608
    // aliases (lifetimes disjoint on the sequential stream):
    short* K_up    = x_bf;      // x_bf dead after the three x-GEMMs
    short* V_up    = ctx_bf;    // consumed by vup_transpose before flash writes
    // total ~122 MiB

    dim3 blk(256);

    // casts to bf16
    cast_bf<<<4096, blk, 0, stream>>>(x, x_bf, 1048576);
    cast_bf<<<512,  blk, 0, stream>>>(W_DKV, wdkv_bf, 131072);
    cast_bf<<<1024, blk, 0, stream>>>(W_KRope, wkr_bf, 262144);
    cast_bf<<<3072, blk, 0, stream>>>(W_Q, wq_bf, 786432);
    cast_bf<<<2048, blk, 0, stream>>>(W_O, wo_bf, 524288);
    cast_bf<<<512,  blk, 0, stream>>>(W_UK, wuk_bf, 131072);
    cast_bf<<<512,  blk, 0, stream>>>(W_UV, wuv_bf, 131072);

    // projections from x (x_bf dead afterwards)
    gemm_bf<<<dim3(3072/128, 32), blk, 0, stream>>>(
        x_bf, wq_bf, nullptr, q_bf, 3072, 2048);
    gemm_bf<<<dim3(1024/128, 32), blk, 0, stream>>>(
        x_bf, wkr_bf, nullptr, kr_bf, 1024, 2048);
    gemm_bf<<<dim3(512/128, 32), blk, 0, stream>>>(
        x_bf, wdkv_bf, c_kv, nullptr, 512, 2048);
    rmsnorm_bf<<<4096, blk, 0, stream>>>(c_kv, kvnw, c_kv_bf);

    // absorbed K/V up-projections (K_up overwrites x_bf region)
    gemm_bf<<<dim3(2048/128, 32), blk, 0, stream>>>(
        c_kv_bf, wuk_bf, nullptr, K_up, 2048, 512);
    gemm_bf<<<dim3(2048/128, 32), blk, 0, stream>>>(
        c_kv_bf, wuv_bf, nullptr, V_up, 2048, 512);
    vup_transpose<<<dim3(32, 32, 2), blk, 0, stream>>>(V_up, V_upT);

    // RoPE in place (bf16)
    rope_kernel<<<8192, blk, 0, stream>>>(q_bf, kr_bf, offp);

    // flash attention -> ctx (bf16); overwrites the V_up alias (already dead)
    flash_mha<<<dim3(S_/128, B_*H_), dim3(512), 0, stream>>>(
        q_bf, K_up, kr_bf, V_upT, offp, ctx_bf);

    // out = ctx @ W_O^T (fp32 out)
    gemm_bf<<<dim3(2048/128, 32), blk, 0, stream>>>(
        ctx_bf, wo_bf, out, nullptr, 2048, 2048);
}

// Round 3
// 528.524 us; speedup vs baseline: 4.3503x; 1.1026x over previous
//
#include <hip/hip_runtime.h>
#include <hip/hip_bf16.h>
#include <math.h>

#define B_    2
#define S_    2048
#define DIN   2048
#define DOUT  2048
#define H_    16
#define RD_   64
#define L_    512
#define HD_   128
#define BS_   (B_*S_)   // 4096

typedef __attribute__((ext_vector_type(8))) short bf16x8;
typedef __attribute__((ext_vector_type(4))) float f32x4;

__device__ __forceinline__ short f2bs(float f) {
    __hip_bfloat16 h = __float2bfloat16(f);
    return *reinterpret_cast<short*>(&h);
}
__device__ __forceinline__ float bs2f(short s) {
    unsigned u = ((unsigned)(unsigned short)s) << 16;
    return __uint_as_float(u);
}

// global -> LDS direct DMA, 16 B per lane. LDS dest is wave-uniform base
// (HW adds lane*16); global src is per-lane (enables source-side swizzle).
__device__ __forceinline__ void gld16(const void* g, void* l) {
    __builtin_amdgcn_global_load_lds(
        (const __attribute__((address_space(1))) unsigned int*)g,
        (__attribute__((address_space(3))) unsigned int*)l, 16, 0, 0);
}

// ---------------------------------------------------------------------------
// fp32 -> bf16 cast, 8 elems/thread. n8 = n/8.
// ---------------------------------------------------------------------------
__global__ __launch_bounds__(256) void cast_bf(const float* __restrict__ in,
                                               short* __restrict__ out, int n8)
{
    int i = blockIdx.x * 256 + threadIdx.x;
    if (i >= n8) return;
    float4 a = ((const float4*)in)[i*2], b = ((const float4*)in)[i*2+1];
    bf16x8 t;
    t[0]=f2bs(a.x); t[1]=f2bs(a.y); t[2]=f2bs(a.z); t[3]=f2bs(a.w);
    t[4]=f2bs(b.x); t[5]=f2bs(b.y); t[6]=f2bs(b.z); t[7]=f2bs(b.w);
    ((bf16x8*)out)[i] = t;
}

// ---------------------------------------------------------------------------
// bf16 MFMA NT GEMM v2 (R8): m97-structure. C[m][n] = sum_k A[m][k]*B[n][k].
// M=grid.y*128, K%32==0. 256 thr = 4 waves (2x2 of 64x64), 16x16x32 MFMA.
// global_load_lds width-16 staging into LINEAR [128][32] LDS tiles;
// bank spread via source-side XOR of the 16B col-group with (row&3)
// (involution; frag reads apply the same XOR). Proven ~1.7x over
// reg-staged padded-pitch staging (ladder step2->step3, 517->874 TF).
// ---------------------------------------------------------------------------
__global__ __launch_bounds__(256, 4) void gemm_bf(
    const short* __restrict__ A, const short* __restrict__ Bw,
    float* __restrict__ Cf, short* __restrict__ Cb, int N, int K)
{
    __shared__ short As[128*32];
    __shared__ short Bs[128*32];
    const int tid = threadIdx.x;
    const int m0 = blockIdx.y << 7, n0 = blockIdx.x << 7;
    const int w = tid >> 6, lane = tid & 63;
    const int quad = lane >> 4, n16 = lane & 15;
    const int mw = (w & 1) << 6, nw = (w >> 1) << 6;
    const int lr = lane >> 2, cg = lane & 3;     // 16 rows x 4 col-groups
    const int swr = (quad ^ (n16 & 3)) << 3;     // frag-read swizzle (shorts)

    f32x4 acc[4][4];
    #pragma unroll
    for (int mt = 0; mt < 4; mt++)
        #pragma unroll
        for (int nt = 0; nt < 4; nt++) acc[mt][nt] = (f32x4){0.f,0.f,0.f,0.f};

    for (int k0 = 0; k0 < K; k0 += 32) {
        #pragma unroll
        for (int jj = 0; jj < 2; jj++) {
            int rb = (jj*4 + w)*16;              // wave-uniform row block
            int r = rb + lr;
            int sc = (cg ^ (r & 3)) << 3;        // source-side swizzle
            gld16(A  + (long long)(m0 + r)*K + k0 + sc, (void*)(As + rb*32));
            gld16(Bw + (long long)(n0 + r)*K + k0 + sc, (void*)(Bs + rb*32));
        }
        __syncthreads();                         // drains vmcnt before barrier
        bf16x8 af[4], bfr[4];
        #pragma unroll
        for (int t = 0; t < 4; t++) {
            af[t]  = *(const bf16x8*)(As + (mw + t*16 + n16)*32 + swr);
            bfr[t] = *(const bf16x8*)(Bs + (nw + t*16 + n16)*32 + swr);
        }
        #pragma unroll
        for (int mt = 0; mt < 4; mt++)
            #pragma unroll
            for (int nt = 0; nt < 4; nt++)
                acc[mt][nt] = __builtin_amdgcn_mfma_f32_16x16x32_bf16(
                                  af[mt], bfr[nt], acc[mt][nt], 0, 0, 0);
        __syncthreads();
    }

    #pragma unroll
    for (int mt = 0; mt < 4; mt++)
        #pragma unroll
        for (int nt = 0; nt < 4; nt++)
            #pragma unroll
            for (int r = 0; r < 4; r++) {
                long long row = m0 + mw + mt*16 + quad*4 + r;
                int col = n0 + nw + nt*16 + n16;
                if (Cf) Cf[row*(long long)N + col] = acc[mt][nt][r];
                else    Cb[row*(long long)N + col] = f2bs(acc[mt][nt][r]);
            }
}

// ---------------------------------------------------------------------------
// RMSNorm rows of 512 (fp32 in) -> bf16 out
// ---------------------------------------------------------------------------
__global__ __launch_bounds__(256) void rmsnorm_bf(const float* __restrict__ ckv,
                                                  const float* __restrict__ w,
                                                  short* __restrict__ out)
{
    const int row = blockIdx.x;
    const int tid = threadIdx.x;
    const float* p = ckv + (long long)row * L_;
    float v0 = p[tid], v1 = p[tid + 256];
    float ss = v0 * v0 + v1 * v1;
    #pragma unroll
    for (int o = 32; o >= 1; o >>= 1) ss += __shfl_xor(ss, o);
    __shared__ float wsum[4];
    if ((tid & 63) == 0) wsum[tid >> 6] = ss;
    __syncthreads();
    float tot = wsum[0] + wsum[1] + wsum[2] + wsum[3];
    float scale = rsqrtf(tot * (1.0f / (float)L_) + 1e-6f);
    out[(long long)row * L_ + tid]       = f2bs(v0 * scale * w[tid]);
    out[(long long)row * L_ + tid + 256] = f2bs(v1 * scale * w[tid + 256]);
}

// ---------------------------------------------------------------------------
// RoPE in place on bf16 q (cols 2048+h*64..) and bf16 kr (head-major cols)
// ---------------------------------------------------------------------------
__global__ __launch_bounds__(256) void rope_kernel(short* __restrict__ q_bf,
                                                   short* __restrict__ kr_bf,
                                                   const int* __restrict__ offp)
{
    const int offset = offp[0];
    long long idx = (long long)blockIdx.x * 256 + threadIdx.x;  // (B*S)*H*32
    int r = (int)(idx & 31);
    long long t = idx >> 5;
    int h = (int)(t % H_);
    long long m = t / H_;
    int s = (int)(m % S_);

    float inv = (float)exp(-9.210340371976184 * ((double)r / 32.0));
    float ang = (float)(offset + s) * inv;
    float sn, cs;
    sincosf(ang, &sn, &cs);

    short* q = q_bf + m * 3072 + DOUT + h * RD_;
    float x1 = bs2f(q[r]), x2 = bs2f(q[r + 32]);
    q[r]      = f2bs(x1 * cs - x2 * sn);
    q[r + 32] = f2bs(x2 * cs + x1 * sn);

    short* kk = kr_bf + m * (H_ * RD_) + h * RD_;
    x1 = bs2f(kk[r]); x2 = bs2f(kk[r + 32]);
    kk[r]      = f2bs(x1 * cs - x2 * sn);
    kk[r + 32] = f2bs(x2 * cs + x1 * sn);
}

// ---------------------------------------------------------------------------
// flash_mha v2 (R8): per-head flash attention, K-dim 192, V-dim 128.
// Grid (S/128, B*H), 512 thr = 8 waves; wave w owns q-rows w*16..w*16+15.
// R8 change vs v1 (evidence: MfmaUtil 10% / VALUBusy 21% / 69% idle =
// latency-bound on the 8 dependent shfl_xor reduction chains per tile):
//   - lrun is LANE-PARTIAL (reduced once at epilogue, not per tile)
//   - max reduce runs only on the defer-max trigger (lane-local max vs
//     mrun+8 -> identical trigger decision as row max; rare after tile 0)
//   -> common path has ZERO cross-lane ops.
// LDS (shorts): KC[2][64][128]@0  KR[2][64][64]@16384  VT[2][128][64]@24576
//               P[8][1152]@40960  -> 100,352 B.
// ---------------------------------------------------------------------------
#define TKC0 0
#define TKR0 16384
#define TVT0 24576
#define TPP0 40960

__global__ __launch_bounds__(512)
__attribute__((amdgpu_waves_per_eu(2, 2)))
void flash_mha(
    const short* __restrict__ q_bf,     // [BS][3072] bf16, rope cols rotated
    const short* __restrict__ K_up,     // [BS][2048] bf16 (h*128+d cols)
    const short* __restrict__ kr_bf,    // [BS][1024] bf16, rotated
    const short* __restrict__ V_upT,    // [B*2048][2048] bf16 (row=h*128+d, col=t)
    const int* __restrict__ offp,
    short* __restrict__ ctx_bf)         // [BS][2048] bf16
{
    __shared__ short lds[50176];
    const int offset = offp[0];
    const int bh = blockIdx.y;
    const int b = bh >> 4, h = bh & 15;
    const int r0 = (int)(gridDim.x - 1 - blockIdx.x) * 128;  // longest first
    const int tid = threadIdx.x;
    const int w = tid >> 6, lane = tid & 63;
    const int quad = lane >> 4, n16 = lane & 15;
    const int rx3 = (n16 & 7) << 3;          // short-offset XOR key (reads)
    const float scale = rsqrtf((float)(HD_ + RD_));

    const int l4 = lane >> 4, g16 = lane & 15;   // 4-rows-of-256B decomp
    const int l8 = lane >> 3, g8 = lane & 7;     // 8-rows-of-128B decomp

    const short* kc_src = K_up  + ((long long)b*S_)*2048 + h*HD_;
    const short* kr_src = kr_bf + ((long long)b*S_)*1024 + h*RD_;
    const short* vt_src = V_upT + ((long long)(b*S_ + h*HD_))*2048;

    // 5 gld16 calls per wave: KC 2 (4 rows each), KR 1 (8 rows), VT 2 (8 rows)
    auto stage = [&](int tk, int bf) {
        #pragma unroll
        for (int j = 0; j < 2; j++) {
            int r4 = (w*2 + j)*4;
            int row = r4 + l4;
            int gs = g16 ^ (row & 7);            // source-side swizzle
            gld16(kc_src + (long long)(tk + row)*2048 + gs*8,
                  (void*)(lds + TKC0 + bf*8192 + r4*128));
        }
        {
            int row = w*8 + l8;
            int gs = g8 ^ (l8 & 7);              // row&7 == l8
            gld16(kr_src + (long long)(tk + row)*1024 + gs*8,
                  (void*)(lds + TKR0 + bf*4096 + w*512));
        }
        #pragma unroll
        for (int j = 0; j < 2; j++) {
            int d8 = (w*2 + j)*8;
            int d = d8 + l8;
            int gs = g8 ^ (l8 & 7);              // d&7 == l8
            gld16(vt_src + (long long)d*2048 + tk + gs*8,
                  (void*)(lds + TVT0 + bf*8192 + d8*64));
        }
    };

    stage(0, 0);

    // Q fragments straight from global (one-time): content 4 + rope 2
    bf16x8 qf[6];
    {
        const short* qp = q_bf + ((long long)(b*S_ + r0 + w*16 + n16))*3072;
        #pragma unroll
        for (int ks = 0; ks < 4; ks++)
            qf[ks] = *(const bf16x8*)(qp + h*HD_ + ks*32 + quad*8);
        #pragma unroll
        for (int ks = 0; ks < 2; ks++)
            qf[4+ks] = *(const bf16x8*)(qp + DOUT + h*RD_ + ks*32 + quad*8);
    }

    f32x4 Oacc[8];
    #pragma unroll
    for (int v = 0; v < 8; v++) Oacc[v] = (f32x4){0.f,0.f,0.f,0.f};
    float mrun[4] = {-INFINITY,-INFINITY,-INFINITY,-INFINITY};
    float lrun[4] = {0.f,0.f,0.f,0.f};   // lane-partial sums

    int tmax = r0 + 128 + offset;
    if (tmax > S_) tmax = S_;

    for (int t0 = 0, bf = 0; t0 < tmax; t0 += 64, bf ^= 1) {
        // own stage(t0) loads landed; barrier -> everyone's landed, and
        // everyone is done reading buffer bf^1 (so it can be overwritten)
        asm volatile("s_waitcnt vmcnt(0)" ::: "memory");
        __builtin_amdgcn_s_barrier();
        __builtin_amdgcn_sched_barrier(0);

        if (t0 + 64 < tmax) stage(t0 + 64, bf ^ 1);   // hides under this tile

        // ---- scores: S[16 rows][64 tok], K-dim 192 ----
        const short* kcb = lds + TKC0 + bf*8192;
        const short* krb = lds + TKR0 + bf*4096;
        f32x4 Sf[4];
        #pragma unroll
        for (int nt = 0; nt < 4; nt++) {
            f32x4 a = {0.f,0.f,0.f,0.f};
            const short* kc = kcb + (nt*16 + n16)*128;
            #pragma unroll
            for (int ks = 0; ks < 4; ks++)
                a = __builtin_amdgcn_mfma_f32_16x16x32_bf16(
                        qf[ks], *(const bf16x8*)(kc + ((ks*32 + quad*8) ^ rx3)),
                        a, 0, 0, 0);
            const short* kr = krb + (nt*16 + n16)*64;
            a = __builtin_amdgcn_mfma_f32_16x16x32_bf16(
                    qf[4], *(const bf16x8*)(kr + ((quad*8) ^ rx3)), a, 0, 0, 0);
            a = __builtin_amdgcn_mfma_f32_16x16x32_bf16(
                    qf[5], *(const bf16x8*)(kr + ((32 + quad*8) ^ rx3)), a, 0, 0, 0);
            Sf[nt] = a;
        }

        // ---- softmax: defer-max, zero cross-lane ops in the common path ----
        float e0[4][4], lm[4];
        #pragma unroll
        for (int r = 0; r < 4; r++) {
            const int srow = r0 + w*16 + quad*4 + r;
            lm[r] = -INFINITY;
            #pragma unroll
            for (int nt = 0; nt < 4; nt++) {
                int t = t0 + nt*16 + n16;
                float s = (t <= srow + offset) ? Sf[nt][r]*scale : -INFINITY;
                e0[r][nt] = s;
                lm[r] = fmaxf(lm[r], s);
            }
        }
        bool trig = (lm[0] > mrun[0] + 8.f) | (lm[1] > mrun[1] + 8.f)
                  | (lm[2] > mrun[2] + 8.f) | (lm[3] > mrun[3] + 8.f);
        if (__any((int)trig)) {          // rare after the first tile
            float al[4];
            #pragma unroll
            for (int r = 0; r < 4; r++) {
                float tm = lm[r];
                tm = fmaxf(tm, __shfl_xor(tm, 1));
                tm = fmaxf(tm, __shfl_xor(tm, 2));
                tm = fmaxf(tm, __shfl_xor(tm, 4));
                tm = fmaxf(tm, __shfl_xor(tm, 8));
                if (tm > mrun[r]) { al[r] = __expf(mrun[r] - tm); mrun[r] = tm; }
                else al[r] = 1.f;
            }
            #pragma unroll
            for (int v = 0; v < 8; v++) {
                Oacc[v][0] *= al[0]; Oacc[v][1] *= al[1];
                Oacc[v][2] *= al[2]; Oacc[v][3] *= al[3];
            }
            lrun[0] *= al[0]; lrun[1] *= al[1];
            lrun[2] *= al[2]; lrun[3] *= al[3];
        }
        #pragma unroll
        for (int r = 0; r < 4; r++) {
            float ps = 0.f;
            #pragma unroll
            for (int nt = 0; nt < 4; nt++) {
                float ex = __expf(e0[r][nt] - mrun[r]);
                ps += ex;
                lds[TPP0 + w*1152 + (quad*4 + r)*72 + nt*16 + n16] = f2bs(ex);
            }
            lrun[r] += ps;               // lane-partial, no shuffle
        }

        // ---- PV: O[16 rows][128 dims] += P @ V ----  (P is wave-private)
        const short* vtb = lds + TVT0 + bf*8192;
        bf16x8 pf0 = *(const bf16x8*)(lds + TPP0 + w*1152 + n16*72 + quad*8);
        bf16x8 pf1 = *(const bf16x8*)(lds + TPP0 + w*1152 + n16*72 + 32 + quad*8);
        const int vo0 = (quad*8) ^ rx3, vo1 = (32 + quad*8) ^ rx3;
        #pragma unroll
        for (int v = 0; v < 8; v++) {
            const short* vb = vtb + (v*16 + n16)*64;
            Oacc[v] = __builtin_amdgcn_mfma_f32_16x16x32_bf16(
                          pf0, *(const bf16x8*)(vb + vo0), Oacc[v], 0, 0, 0);
            Oacc[v] = __builtin_amdgcn_mfma_f32_16x16x32_bf16(
                          pf1, *(const bf16x8*)(vb + vo1), Oacc[v], 0, 0, 0);
        }
    }

    // ---- epilogue: one-time lrun reduce, then ctx = O/l direct store ----
    float inv[4];
    #pragma unroll
    for (int r = 0; r < 4; r++) {
        float s = lrun[r];
        s += __shfl_xor(s, 1);
        s += __shfl_xor(s, 2);
        s += __shfl_xor(s, 4);
        s += __shfl_xor(s, 8);
        inv[r] = 1.0f / s;
    }
    #pragma unroll
    for (int v = 0; v < 8; v++)
        #pragma unroll
        for (int r = 0; r < 4; r++) {
            long long row = (long long)b*S_ + r0 + w*16 + quad*4 + r;
            ctx_bf[row*2048 + h*HD_ + v*16 + n16] = f2bs(Oacc[v][r]*inv[r]);
        }
}

// ---------------------------------------------------------------------------
extern "C" void kernel_launch(void* const* d_in, const int* in_sizes, int n_in,
                              void* d_out, int out_size, void* d_ws, size_t ws_size,
                              hipStream_t stream)
{
    const float* x       = (const float*)d_in[0];
    const float* W_DKV   = (const float*)d_in[1];
    const float* W_KRope = (const float*)d_in[2];
    const float* W_Q     = (const float*)d_in[3];
    const float* W_UK    = (const float*)d_in[4];
    const float* W_UV    = (const float*)d_in[5];
    const float* W_O     = (const float*)d_in[6];
    const float* kvnw    = (const float*)d_in[7];
    const int*   offp    = (const int*)d_in[8];
    float* out = (float*)d_out;

    float* ws = (float*)d_ws;
    float* c_kv    = ws;                        // 2,097,152 f
    short* x_bf    = (short*)(c_kv + 2097152);  // 8,388,608
    short* q_bf    = x_bf    + 8388608;         // 12,582,912
    short* kr_bf   = q_bf    + 12582912;        // 4,194,304
    short* c_kv_bf = kr_bf   + 4194304;         // 2,097,152
    short* wuk_bf  = c_kv_bf + 2097152;         // 1,048,576
    short* wuv_bf  = wuk_bf  + 1048576;         // 1,048,576
    short* wdkv_bf = wuv_bf  + 1048576;         // 1,048,576
    short* wkr_bf  = wdkv_bf + 1048576;         // 2,097,152
    short* wq_bf   = wkr_bf  + 2097152;         // 6,291,456
    short* wo_bf   = wq_bf   + 6291456;         // 4,194,304
    short* ctx_bf  = wo_bf   + 4194304;         // 8,388,608
    short* V_upT   = ctx_bf  + 8388608;         // 8,388,608
    // alias (lifetimes disjoint on the sequential stream):
    short* K_up    = x_bf;      // x_bf dead after the three x-GEMMs
    // total ~122 MiB

    dim3 blk(256);

    // casts to bf16
    cast_bf<<<4096, blk, 0, stream>>>(x, x_bf, 1048576);
    cast_bf<<<512,  blk, 0, stream>>>(W_DKV, wdkv_bf, 131072);
    cast_bf<<<1024, blk, 0, stream>>>(W_KRope, wkr_bf, 262144);
    cast_bf<<<3072, blk, 0, stream>>>(W_Q, wq_bf, 786432);
    cast_bf<<<2048, blk, 0, stream>>>(W_O, wo_bf, 524288);
    cast_bf<<<512,  blk, 0, stream>>>(W_UK, wuk_bf, 131072);
    cast_bf<<<512,  blk, 0, stream>>>(W_UV, wuv_bf, 131072);

    // projections from x (x_bf dead afterwards)
    gemm_bf<<<dim3(3072/128, 32), blk, 0, stream>>>(
        x_bf, wq_bf, nullptr, q_bf, 3072, 2048);
    gemm_bf<<<dim3(1024/128, 32), blk, 0, stream>>>(
        x_bf, wkr_bf, nullptr, kr_bf, 1024, 2048);
    gemm_bf<<<dim3(512/128, 32), blk, 0, stream>>>(
        x_bf, wdkv_bf, c_kv, nullptr, 512, 2048);
    rmsnorm_bf<<<4096, blk, 0, stream>>>(c_kv, kvnw, c_kv_bf);

    // absorbed K/V up-projections (K_up overwrites x_bf region).
    // V_upT is computed DIRECTLY as W_UV @ c_kv^T per batch (same FLOPs as
    // V_up + transpose; kills the vup_transpose kernel).
    gemm_bf<<<dim3(2048/128, 32), blk, 0, stream>>>(
        c_kv_bf, wuk_bf, nullptr, K_up, 2048, 512);
    gemm_bf<<<dim3(2048/128, 16), blk, 0, stream>>>(
        wuv_bf, c_kv_bf, nullptr, V_upT, 2048, 512);
    gemm_bf<<<dim3(2048/128, 16), blk, 0, stream>>>(
        wuv_bf, c_kv_bf + (long long)S_*512, nullptr,
        V_upT + (long long)S_*2048, 2048, 512);

    // RoPE in place (bf16)
    rope_kernel<<<8192, blk, 0, stream>>>(q_bf, kr_bf, offp);

    // flash attention -> ctx (bf16)
    flash_mha<<<dim3(S_/128, B_*H_), dim3(512), 0, stream>>>(
        q_bf, K_up, kr_bf, V_upT, offp, ctx_bf);

    // out = ctx @ W_O^T (fp32 out)
    gemm_bf<<<dim3(2048/128, 32), blk, 0, stream>>>(
        ctx_bf, wo_bf, out, nullptr, 2048, 2048);
}

// Round 4
// 474.868 us; speedup vs baseline: 4.8418x; 1.1130x over previous
//
#include <hip/hip_runtime.h>
#include <hip/hip_bf16.h>
#include <math.h>

#define B_    2
#define S_    2048
#define DIN   2048
#define DOUT  2048
#define H_    16
#define RD_   64
#define L_    512
#define HD_   128
#define BS_   (B_*S_)   // 4096

typedef __attribute__((ext_vector_type(8))) short bf16x8;
typedef __attribute__((ext_vector_type(4))) float f32x4;

__device__ __forceinline__ short f2bs(float f) {
    __hip_bfloat16 h = __float2bfloat16(f);
    return *reinterpret_cast<short*>(&h);
}
__device__ __forceinline__ float bs2f(short s) {
    unsigned u = ((unsigned)(unsigned short)s) << 16;
    return __uint_as_float(u);
}

// global -> LDS direct DMA, 16 B per lane. LDS dest is wave-uniform base
// (HW adds lane*16); global src is per-lane (enables source-side swizzle).
__device__ __forceinline__ void gld16(const void* g, void* l) {
    __builtin_amdgcn_global_load_lds(
        (const __attribute__((address_space(1))) unsigned int*)g,
        (__attribute__((address_space(3))) unsigned int*)l, 16, 0, 0);
}

// ---------------------------------------------------------------------------
// Fused fp32->bf16 cast of ALL inputs in ONE launch (R9: was 7 launches;
// ~10us/launch boundary overhead was a visible slice of the 385us non-flash
// time). Group = 8 elems. Ladder bounds are cumulative group counts.
// ---------------------------------------------------------------------------
__global__ __launch_bounds__(256) void cast_all(
    const float* __restrict__ x,    const float* __restrict__ wq,
    const float* __restrict__ wkr,  const float* __restrict__ wdkv,
    const float* __restrict__ wo,   const float* __restrict__ wuk,
    const float* __restrict__ wuv,
    short* __restrict__ x_bf,   short* __restrict__ wqkr_bf,
    short* __restrict__ wdkv_bf, short* __restrict__ wo_bf,
    short* __restrict__ wuk_bf,  short* __restrict__ wuv_bf)
{
    long long i = (long long)blockIdx.x * 256 + threadIdx.x;  // 3,014,656 total
    const float* src; short* dst; long long off;
    if      (i < 1048576) { src = x;    dst = x_bf;              off = i; }
    else if (i < 1835008) { src = wq;   dst = wqkr_bf;           off = i - 1048576; }
    else if (i < 2097152) { src = wkr;  dst = wqkr_bf + 6291456; off = i - 1835008; }
    else if (i < 2228224) { src = wdkv; dst = wdkv_bf;           off = i - 2097152; }
    else if (i < 2752512) { src = wo;   dst = wo_bf;             off = i - 2228224; }
    else if (i < 2883584) { src = wuk;  dst = wuk_bf;            off = i - 2752512; }
    else                  { src = wuv;  dst = wuv_bf;            off = i - 2883584; }
    float4 a = ((const float4*)src)[off*2], b = ((const float4*)src)[off*2+1];
    bf16x8 t;
    t[0]=f2bs(a.x); t[1]=f2bs(a.y); t[2]=f2bs(a.z); t[3]=f2bs(a.w);
    t[4]=f2bs(b.x); t[5]=f2bs(b.y); t[6]=f2bs(b.z); t[7]=f2bs(b.w);
    ((bf16x8*)dst)[off] = t;
}

// ---------------------------------------------------------------------------
// bf16 MFMA NT GEMM (m97-structure). C[m][n] = sum_k A[m][k]*B[n][k].
// M=grid.y*128, K%32==0. az/bz/cz: gridDim.z batch strides (elements).
// ---------------------------------------------------------------------------
__global__ __launch_bounds__(256, 4) void gemm_bf(
    const short* __restrict__ A, const short* __restrict__ Bw,
    float* __restrict__ Cf, short* __restrict__ Cb, int N, int K,
    long long az, long long bz, long long cz)
{
    const int z = blockIdx.z;
    A  += (long long)z * az;
    Bw += (long long)z * bz;
    if (Cf) Cf += (long long)z * cz; else Cb += (long long)z * cz;

    __shared__ short As[128*32];
    __shared__ short Bs[128*32];
    const int tid = threadIdx.x;
    const int m0 = blockIdx.y << 7, n0 = blockIdx.x << 7;
    const int w = tid >> 6, lane = tid & 63;
    const int quad = lane >> 4, n16 = lane & 15;
    const int mw = (w & 1) << 6, nw = (w >> 1) << 6;
    const int lr = lane >> 2, cg = lane & 3;     // 16 rows x 4 col-groups
    const int swr = (quad ^ (n16 & 3)) << 3;     // frag-read swizzle (shorts)

    f32x4 acc[4][4];
    #pragma unroll
    for (int mt = 0; mt < 4; mt++)
        #pragma unroll
        for (int nt = 0; nt < 4; nt++) acc[mt][nt] = (f32x4){0.f,0.f,0.f,0.f};

    for (int k0 = 0; k0 < K; k0 += 32) {
        #pragma unroll
        for (int jj = 0; jj < 2; jj++) {
            int rb = (jj*4 + w)*16;              // wave-uniform row block
            int r = rb + lr;
            int sc = (cg ^ (r & 3)) << 3;        // source-side swizzle
            gld16(A  + (long long)(m0 + r)*K + k0 + sc, (void*)(As + rb*32));
            gld16(Bw + (long long)(n0 + r)*K + k0 + sc, (void*)(Bs + rb*32));
        }
        __syncthreads();                         // drains vmcnt before barrier
        bf16x8 af[4], bfr[4];
        #pragma unroll
        for (int t = 0; t < 4; t++) {
            af[t]  = *(const bf16x8*)(As + (mw + t*16 + n16)*32 + swr);
            bfr[t] = *(const bf16x8*)(Bs + (nw + t*16 + n16)*32 + swr);
        }
        #pragma unroll
        for (int mt = 0; mt < 4; mt++)
            #pragma unroll
            for (int nt = 0; nt < 4; nt++)
                acc[mt][nt] = __builtin_amdgcn_mfma_f32_16x16x32_bf16(
                                  af[mt], bfr[nt], acc[mt][nt], 0, 0, 0);
        __syncthreads();
    }

    #pragma unroll
    for (int mt = 0; mt < 4; mt++)
        #pragma unroll
        for (int nt = 0; nt < 4; nt++)
            #pragma unroll
            for (int r = 0; r < 4; r++) {
                long long row = m0 + mw + mt*16 + quad*4 + r;
                int col = n0 + nw + nt*16 + n16;
                if (Cf) Cf[row*(long long)N + col] = acc[mt][nt][r];
                else    Cb[row*(long long)N + col] = f2bs(acc[mt][nt][r]);
            }
}

// ---------------------------------------------------------------------------
// RMSNorm rows of 512 (fp32 in) -> bf16 out
// ---------------------------------------------------------------------------
__global__ __launch_bounds__(256) void rmsnorm_bf(const float* __restrict__ ckv,
                                                  const float* __restrict__ w,
                                                  short* __restrict__ out)
{
    const int row = blockIdx.x;
    const int tid = threadIdx.x;
    const float* p = ckv + (long long)row * L_;
    float v0 = p[tid], v1 = p[tid + 256];
    float ss = v0 * v0 + v1 * v1;
    #pragma unroll
    for (int o = 32; o >= 1; o >>= 1) ss += __shfl_xor(ss, o);
    __shared__ float wsum[4];
    if ((tid & 63) == 0) wsum[tid >> 6] = ss;
    __syncthreads();
    float tot = wsum[0] + wsum[1] + wsum[2] + wsum[3];
    float scale = rsqrtf(tot * (1.0f / (float)L_) + 1e-6f);
    out[(long long)row * L_ + tid]       = f2bs(v0 * scale * w[tid]);
    out[(long long)row * L_ + tid + 256] = f2bs(v1 * scale * w[tid + 256]);
}

// ---------------------------------------------------------------------------
// RoPE in place on the fused q/kr buffer qkr[BS][4096]:
//   q-rope cols 2048 + h*64 .. ; k-rope cols 3072 + h*64 ..
// R9: inv-freq via float __expf (was DOUBLE exp -> software f64 exp per
// thread, ~2.1M of them). Angle err <= ~2e-3 rad < bf16 quantum.
// ---------------------------------------------------------------------------
__global__ __launch_bounds__(256) void rope_kernel(short* __restrict__ qkr,
                                                   const int* __restrict__ offp)
{
    const int offset = offp[0];
    long long idx = (long long)blockIdx.x * 256 + threadIdx.x;  // (B*S)*H*32
    int r = (int)(idx & 31);
    long long t = idx >> 5;
    int h = (int)(t % H_);
    long long m = t / H_;
    int s = (int)(m % S_);

    float inv = __expf(-0.28782314f * (float)r);   // ln(10000)/32
    float ang = (float)(offset + s) * inv;
    float sn, cs;
    sincosf(ang, &sn, &cs);

    short* q = qkr + m * 4096 + 2048 + h * RD_;
    float x1 = bs2f(q[r]), x2 = bs2f(q[r + 32]);
    q[r]      = f2bs(x1 * cs - x2 * sn);
    q[r + 32] = f2bs(x2 * cs + x1 * sn);

    short* kk = qkr + m * 4096 + 3072 + h * RD_;
    x1 = bs2f(kk[r]); x2 = bs2f(kk[r + 32]);
    kk[r]      = f2bs(x1 * cs - x2 * sn);
    kk[r + 32] = f2bs(x2 * cs + x1 * sn);
}

// ---------------------------------------------------------------------------
// flash_mha v3 (R9): per-head flash attention, K-dim 192, V-dim 128.
// Grid (S/128, B*H), 512 thr = 8 waves; wave w owns q-rows w*16..w*16+15.
// R9 change vs v2 (evidence: MfmaUtil 12.5%, VALUBusy 22% -> still ~450cyc
// stall/tile: the tile-top vmcnt(0) waits on a stage issued only ~450cyc of
// compute earlier, vs ~900cyc HBM latency):
//   DEPTH-2 PIPELINE: 3 LDS tile-buffers (40KB each); prefetch stage(t+2)
//   inside tile t; tile-top wait is vmcnt(5) (= the 5 DMAs of stage(t+1)
//   still in flight), so stage(t) has had TWO tiles of compute to land.
//   Buffer (bi+2)%3 was last read in tile t-1, whose compute completed
//   before this tile's barrier -> overwrite is safe.
// LDS (shorts): per-buf [KC 64x128 | KR 64x64 | VT 128x64] = 20480;
// 3 bufs + P[8][1152] @61440 -> 141,312 B (1 block/CU, 2 waves/SIMD).
// ---------------------------------------------------------------------------
#define SBUF 20480
#define TPP0 61440

__global__ __launch_bounds__(512)
__attribute__((amdgpu_waves_per_eu(2, 2)))
void flash_mha(
    const short* __restrict__ qkr,      // [BS][4096] bf16 (q 3072 | kr 1024), rotated
    const short* __restrict__ K_up,     // [BS][2048] bf16 (h*128+d cols)
    const short* __restrict__ V_upT,    // [B*2048][2048] bf16 (row=h*128+d, col=t)
    const int* __restrict__ offp,
    short* __restrict__ ctx_bf)         // [BS][2048] bf16
{
    __shared__ short lds[70656];
    const int offset = offp[0];
    const int bh = blockIdx.y;
    const int b = bh >> 4, h = bh & 15;
    const int r0 = (int)(gridDim.x - 1 - blockIdx.x) * 128;  // longest first
    const int tid = threadIdx.x;
    const int w = tid >> 6, lane = tid & 63;
    const int quad = lane >> 4, n16 = lane & 15;
    const int rx3 = (n16 & 7) << 3;          // short-offset XOR key (reads)
    const float scale = rsqrtf((float)(HD_ + RD_));

    const int l4 = lane >> 4, g16 = lane & 15;   // 4-rows-of-256B decomp
    const int l8 = lane >> 3, g8 = lane & 7;     // 8-rows-of-128B decomp

    const short* kc_src = K_up  + ((long long)b*S_)*2048 + h*HD_;
    const short* kr_src = qkr   + ((long long)b*S_)*4096 + 3072 + h*RD_;
    const short* vt_src = V_upT + ((long long)(b*S_ + h*HD_))*2048;

    // 5 gld16 calls per wave: KC 2 (4 rows each), KR 1 (8 rows), VT 2 (8 rows)
    auto stage = [&](int tk, int bi) {
        short* base = lds + bi*SBUF;
        #pragma unroll
        for (int j = 0; j < 2; j++) {
            int r4 = (w*2 + j)*4;
            int row = r4 + l4;
            int gs = g16 ^ (row & 7);            // source-side swizzle
            gld16(kc_src + (long long)(tk + row)*2048 + gs*8,
                  (void*)(base + r4*128));
        }
        {
            int row = w*8 + l8;
            int gs = g8 ^ (l8 & 7);              // row&7 == l8
            gld16(kr_src + (long long)(tk + row)*4096 + gs*8,
                  (void*)(base + 8192 + w*512));
        }
        #pragma unroll
        for (int j = 0; j < 2; j++) {
            int d8 = (w*2 + j)*8;
            int d = d8 + l8;
            int gs = g8 ^ (l8 & 7);              // d&7 == l8
            gld16(vt_src + (long long)d*2048 + tk + gs*8,
                  (void*)(base + 12288 + d8*64));
        }
    };

    // Q fragments first (oldest vm ops -> drained by tile-0's vmcnt wait)
    bf16x8 qf[6];
    {
        const short* qp = qkr + ((long long)(b*S_ + r0 + w*16 + n16))*4096;
        #pragma unroll
        for (int ks = 0; ks < 4; ks++)
            qf[ks] = *(const bf16x8*)(qp + h*HD_ + ks*32 + quad*8);
        qf[4] = *(const bf16x8*)(qp + 2048 + h*RD_ + quad*8);
        qf[5] = *(const bf16x8*)(qp + 2048 + h*RD_ + 32 + quad*8);
    }

    int tmax = r0 + 128 + offset;
    if (tmax > S_) tmax = S_;        // always >= 128 -> both prologue stages valid

    stage(0, 0);
    stage(64, 1);

    f32x4 Oacc[8];
    #pragma unroll
    for (int v = 0; v < 8; v++) Oacc[v] = (f32x4){0.f,0.f,0.f,0.f};
    float mrun[4] = {-INFINITY,-INFINITY,-INFINITY,-INFINITY};
    float lrun[4] = {0.f,0.f,0.f,0.f};   // lane-partial sums

    int bi = 0;
    for (int t0 = 0; t0 < tmax; t0 += 64) {
        // stage(t0) done; stage(t0+64)'s 5 DMAs may stay in flight
        if (t0 + 64 < tmax) asm volatile("s_waitcnt vmcnt(5)" ::: "memory");
        else                asm volatile("s_waitcnt vmcnt(0)" ::: "memory");
        __builtin_amdgcn_s_barrier();
        __builtin_amdgcn_sched_barrier(0);

        {   // prefetch depth 2 into the buffer tile t0-64 just finished with
            int bi2 = bi + 2; if (bi2 >= 3) bi2 -= 3;
            if (t0 + 128 < tmax) stage(t0 + 128, bi2);
        }

        const short* kcb = lds + bi*SBUF;
        const short* krb = kcb + 8192;
        const short* vtb = kcb + 12288;

        // ---- scores: S[16 rows][64 tok], K-dim 192 ----
        f32x4 Sf[4];
        #pragma unroll
        for (int nt = 0; nt < 4; nt++) {
            f32x4 a = {0.f,0.f,0.f,0.f};
            const short* kc = kcb + (nt*16 + n16)*128;
            #pragma unroll
            for (int ks = 0; ks < 4; ks++)
                a = __builtin_amdgcn_mfma_f32_16x16x32_bf16(
                        qf[ks], *(const bf16x8*)(kc + ((ks*32 + quad*8) ^ rx3)),
                        a, 0, 0, 0);
            const short* kr = krb + (nt*16 + n16)*64;
            a = __builtin_amdgcn_mfma_f32_16x16x32_bf16(
                    qf[4], *(const bf16x8*)(kr + ((quad*8) ^ rx3)), a, 0, 0, 0);
            a = __builtin_amdgcn_mfma_f32_16x16x32_bf16(
                    qf[5], *(const bf16x8*)(kr + ((32 + quad*8) ^ rx3)), a, 0, 0, 0);
            Sf[nt] = a;
        }

        // ---- softmax: defer-max, zero cross-lane ops in the common path ----
        float e0[4][4], lm[4];
        #pragma unroll
        for (int r = 0; r < 4; r++) {
            const int srow = r0 + w*16 + quad*4 + r;
            lm[r] = -INFINITY;
            #pragma unroll
            for (int nt = 0; nt < 4; nt++) {
                int t = t0 + nt*16 + n16;
                float s = (t <= srow + offset) ? Sf[nt][r]*scale : -INFINITY;
                e0[r][nt] = s;
                lm[r] = fmaxf(lm[r], s);
            }
        }
        bool trig = (lm[0] > mrun[0] + 8.f) | (lm[1] > mrun[1] + 8.f)
                  | (lm[2] > mrun[2] + 8.f) | (lm[3] > mrun[3] + 8.f);
        if (__any((int)trig)) {          // rare after the first tile
            float al[4];
            #pragma unroll
            for (int r = 0; r < 4; r++) {
                float tm = lm[r];
                tm = fmaxf(tm, __shfl_xor(tm, 1));
                tm = fmaxf(tm, __shfl_xor(tm, 2));
                tm = fmaxf(tm, __shfl_xor(tm, 4));
                tm = fmaxf(tm, __shfl_xor(tm, 8));
                if (tm > mrun[r]) { al[r] = __expf(mrun[r] - tm); mrun[r] = tm; }
                else al[r] = 1.f;
            }
            #pragma unroll
            for (int v = 0; v < 8; v++) {
                Oacc[v][0] *= al[0]; Oacc[v][1] *= al[1];
                Oacc[v][2] *= al[2]; Oacc[v][3] *= al[3];
            }
            lrun[0] *= al[0]; lrun[1] *= al[1];
            lrun[2] *= al[2]; lrun[3] *= al[3];
        }
        #pragma unroll
        for (int r = 0; r < 4; r++) {
            float ps = 0.f;
            #pragma unroll
            for (int nt = 0; nt < 4; nt++) {
                float ex = __expf(e0[r][nt] - mrun[r]);
                ps += ex;
                lds[TPP0 + w*1152 + (quad*4 + r)*72 + nt*16 + n16] = f2bs(ex);
            }
            lrun[r] += ps;               // lane-partial, no shuffle
        }

        // ---- PV: O[16 rows][128 dims] += P @ V ----  (P is wave-private)
        bf16x8 pf0 = *(const bf16x8*)(lds + TPP0 + w*1152 + n16*72 + quad*8);
        bf16x8 pf1 = *(const bf16x8*)(lds + TPP0 + w*1152 + n16*72 + 32 + quad*8);
        const int vo0 = (quad*8) ^ rx3, vo1 = (32 + quad*8) ^ rx3;
        #pragma unroll
        for (int v = 0; v < 8; v++) {
            const short* vb = vtb + (v*16 + n16)*64;
            Oacc[v] = __builtin_amdgcn_mfma_f32_16x16x32_bf16(
                          pf0, *(const bf16x8*)(vb + vo0), Oacc[v], 0, 0, 0);
            Oacc[v] = __builtin_amdgcn_mfma_f32_16x16x32_bf16(
                          pf1, *(const bf16x8*)(vb + vo1), Oacc[v], 0, 0, 0);
        }

        bi = bi + 1; if (bi >= 3) bi = 0;
    }

    // ---- epilogue: one-time lrun reduce, then ctx = O/l direct store ----
    float inv[4];
    #pragma unroll
    for (int r = 0; r < 4; r++) {
        float s = lrun[r];
        s += __shfl_xor(s, 1);
        s += __shfl_xor(s, 2);
        s += __shfl_xor(s, 4);
        s += __shfl_xor(s, 8);
        inv[r] = 1.0f / s;
    }
    #pragma unroll
    for (int v = 0; v < 8; v++)
        #pragma unroll
        for (int r = 0; r < 4; r++) {
            long long row = (long long)b*S_ + r0 + w*16 + quad*4 + r;
            ctx_bf[row*2048 + h*HD_ + v*16 + n16] = f2bs(Oacc[v][r]*inv[r]);
        }
}

// ---------------------------------------------------------------------------
extern "C" void kernel_launch(void* const* d_in, const int* in_sizes, int n_in,
                              void* d_out, int out_size, void* d_ws, size_t ws_size,
                              hipStream_t stream)
{
    const float* x       = (const float*)d_in[0];
    const float* W_DKV   = (const float*)d_in[1];
    const float* W_KRope = (const float*)d_in[2];
    const float* W_Q     = (const float*)d_in[3];
    const float* W_UK    = (const float*)d_in[4];
    const float* W_UV    = (const float*)d_in[5];
    const float* W_O     = (const float*)d_in[6];
    const float* kvnw    = (const float*)d_in[7];
    const int*   offp    = (const int*)d_in[8];
    float* out = (float*)d_out;

    float* ws = (float*)d_ws;
    float* c_kv    = ws;                        // 2,097,152 f
    short* x_bf    = (short*)(c_kv + 2097152);  // 8,388,608
    short* qkr_bf  = x_bf    + 8388608;         // 16,777,216  [4096][4096]
    short* c_kv_bf = qkr_bf  + 16777216;        // 2,097,152
    short* wuk_bf  = c_kv_bf + 2097152;         // 1,048,576
    short* wuv_bf  = wuk_bf  + 1048576;         // 1,048,576
    short* wdkv_bf = wuv_bf  + 1048576;         // 1,048,576
    short* wqkr_bf = wdkv_bf + 1048576;         // 8,388,608  [4096][2048]
    short* wo_bf   = wqkr_bf + 8388608;         // 4,194,304
    short* ctx_bf  = wo_bf   + 4194304;         // 8,388,608
    short* V_upT   = ctx_bf  + 8388608;         // 8,388,608
    // alias (lifetimes disjoint on the sequential stream):
    short* K_up    = x_bf;      // x_bf dead after the two x-GEMMs
    // total ~122 MiB

    dim3 blk(256);

    // one fused cast (7 -> 1 launch)
    cast_all<<<11776, blk, 0, stream>>>(
        x, W_Q, W_KRope, W_DKV, W_O, W_UK, W_UV,
        x_bf, wqkr_bf, wdkv_bf, wo_bf, wuk_bf, wuv_bf);

    // fused Q+KRope projection: [4096]x[4096] = x @ [W_Q;W_KRope]^T
    gemm_bf<<<dim3(32, 32), blk, 0, stream>>>(
        x_bf, wqkr_bf, nullptr, qkr_bf, 4096, 2048, 0, 0, 0);
    // c_kv (fp32 out for rmsnorm precision)
    gemm_bf<<<dim3(4, 32), blk, 0, stream>>>(
        x_bf, wdkv_bf, c_kv, nullptr, 512, 2048, 0, 0, 0);
    rmsnorm_bf<<<4096, blk, 0, stream>>>(c_kv, kvnw, c_kv_bf);

    // absorbed K/V up-projections (K_up overwrites x_bf region).
    gemm_bf<<<dim3(16, 32), blk, 0, stream>>>(
        c_kv_bf, wuk_bf, nullptr, K_up, 2048, 512, 0, 0, 0);
    // V_upT = W_UV @ c_kv^T, both batches in one launch via grid.z
    gemm_bf<<<dim3(16, 16, 2), blk, 0, stream>>>(
        wuv_bf, c_kv_bf, nullptr, V_upT, 2048, 512,
        0, (long long)S_*512, (long long)S_*2048);

    // RoPE in place on the fused buffer
    rope_kernel<<<8192, blk, 0, stream>>>(qkr_bf, offp);

    // flash attention -> ctx (bf16)
    flash_mha<<<dim3(S_/128, B_*H_), dim3(512), 0, stream>>>(
        qkr_bf, K_up, V_upT, offp, ctx_bf);

    // out = ctx @ W_O^T (fp32 out)
    gemm_bf<<<dim3(16, 32), blk, 0, stream>>>(
        ctx_bf, wo_bf, out, nullptr, 2048, 2048, 0, 0, 0);
}